// Round 5
// baseline (952.605 us; speedup 1.0000x reference)
//
#include <hip/hip_runtime.h>
#include <cfloat>
#include <cmath>

#define N_NODES 20000
#define MAXD 32
#define F 128

// ---------------- stage 1: trimmed-mean aggregation (register version) -------

// Batcher odd-even mergesort network, ascending, fully unrolled.
// CE counts: SZ=4:5, 8:19, 16:63, 32:191.
template <int SZ>
__device__ __forceinline__ void oe_sort(float (&a)[SZ]) {
#pragma unroll
  for (int p = 1; p < SZ; p <<= 1) {
#pragma unroll
    for (int q = p; q >= 1; q >>= 1) {
#pragma unroll
      for (int j = q % p; j <= SZ - 1 - q; j += 2 * q) {
#pragma unroll
        for (int i = 0; i < q; ++i) {
          int x = i + j, y = i + j + q;
          if (y < SZ && (x / (2 * p)) == (y / (2 * p))) {
            float mn = fminf(a[x], a[y]);
            float mx = fmaxf(a[x], a[y]);
            a[x] = mn;
            a[y] = mx;
          }
        }
      }
    }
  }
}

// extract element at (wave-uniform) position p from a statically-indexed register array
template <int SZ>
__device__ __forceinline__ float extract_pos(const float (&k)[SZ], int p) {
  float sel[SZ];
#pragma unroll
  for (int i = 0; i < SZ; ++i) sel[i] = k[i];
#pragma unroll
  for (int w = SZ >> 1; w >= 1; w >>= 1) {
    bool take = (p & w) != 0;
#pragma unroll
    for (int i = 0; i < w; ++i) sel[i] = take ? sel[i + w] : sel[i];
  }
  return sel[0];
}

// Exact trimmed sum: payloads (key*norm_src) whose STABLE rank (key asc, ties
// by slot — matches jnp.argsort) lies in [b, n-b).
// Fast path: when sorted[b-1] < sorted[b] and sorted[n-b-1] < sorted[n-b],
// rank-membership == value-membership in [lo, hi] (exact, incl. lo==hi runs).
// Slow path (rare boundary ties): exact stable-rank scan.
template <int SZ>
__device__ __forceinline__ float trimmed_sum(const float* __restrict__ h,
                                             const float* __restrict__ norm,
                                             const int* __restrict__ nbr_row,
                                             int n, int f, int b) {
  float ko[SZ];
  float nrm[SZ];  // wave-uniform -> SGPRs
#pragma unroll
  for (int d = 0; d < SZ; ++d) {
    if (d < n) {  // uniform branch (n wave-uniform)
      int src = nbr_row[d];       // scalar load
      nrm[d] = norm[src];         // scalar load
      ko[d] = h[src * F + f];     // vector load, coalesced 256B/wave
    } else {
      nrm[d] = 0.f;
      ko[d] = FLT_MAX;            // pads sort past all valid keys
    }
  }

  float k[SZ];
#pragma unroll
  for (int d = 0; d < SZ; ++d) k[d] = ko[d];
  oe_sort<SZ>(k);

  const float lo  = extract_pos<SZ>(k, b);          // rank b (kept)
  const float hi  = extract_pos<SZ>(k, n - b - 1);  // rank n-b-1 (kept)
  const float lom = extract_pos<SZ>(k, b - 1);      // rank b-1 (trimmed)
  const float him = extract_pos<SZ>(k, n - b);      // rank n-b (trimmed)

  float sum = 0.f;
  if ((lom < lo) & (hi < him)) {
#pragma unroll
    for (int d = 0; d < SZ; ++d) {
      bool keep = (ko[d] >= lo) & (ko[d] <= hi);  // pads (FLT_MAX) fail
      sum = fmaf(keep ? ko[d] : 0.f, nrm[d], sum);
    }
  } else {
    int c_lt_lo = 0, c_lt_hi = 0;
#pragma unroll
    for (int d = 0; d < SZ; ++d) {
      c_lt_lo += (ko[d] < lo) ? 1 : 0;
      c_lt_hi += (ko[d] < hi) ? 1 : 0;
    }
    int run_lo = 0, run_hi = 0;
    const int nb = n - b;
#pragma unroll
    for (int d = 0; d < SZ; ++d) {
      const float kd = ko[d];
      const float m = kd * nrm[d];  // pads: FLT_MAX*0 = 0
      const bool eql = (kd == lo);
      const bool eqh = (kd == hi);
      const bool lh = (lo < hi);
      const bool btw = (kd > lo) & (kd < hi);
      const int r_lo = c_lt_lo + run_lo;  // stable rank if kd==lo
      const int r_hi = c_lt_hi + run_hi;  // stable rank if kd==hi
      const bool inc = btw
                     | (eql & (r_lo >= b) & (lh | (r_lo < nb)))
                     | (lh & eqh & (r_hi < nb));
      sum += inc ? m : 0.f;
      run_lo += eql ? 1 : 0;
      run_hi += eqh ? 1 : 0;
    }
  }
  return sum;
}

// 256 threads = 2 nodes per block (4 waves) — fills per-CU wave slots better
// than 2-wave blocks. All control flow is wave-uniform (node per wave-pair).
__global__ __launch_bounds__(256) void gcn_stage1(const float* __restrict__ h,
                                                  const float* __restrict__ norm,
                                                  const int* __restrict__ nbr,
                                                  const int* __restrict__ deg,
                                                  float* __restrict__ accum) {
  const int t = threadIdx.x;
  const int i = blockIdx.x * 2 + (t >> 7);
  const int f = t & 127;
  const int n = deg[i];            // wave-uniform
  const float ni = norm[i];
  const float hif = h[i * F + f];
  const int idx = i * F + f;

  if (n <= 3) {  // N_NEIGH_THRESHOLD branch
    accum[idx] = (float)n * hif * ni * ni;
    return;
  }

  int b = n / 2 - (1 - (n & 1));
  int bcap = (int)floorf((float)n * 0.45f);
  b = b < bcap ? b : bcap;
  b = b > 1 ? b : 1;

  const int* nbr_row = nbr + i * MAXD;
  float ts;
  if (n <= 4)       ts = trimmed_sum<4>(h, norm, nbr_row, n, f, b);
  else if (n <= 8)  ts = trimmed_sum<8>(h, norm, nbr_row, n, f, b);
  else if (n <= 16) ts = trimmed_sum<16>(h, norm, nbr_row, n, f, b);
  else              ts = trimmed_sum<32>(h, norm, nbr_row, n, f, b);

  accum[idx] = (ts + hif * ni * (float)(2 * b)) * ni;
}

// ---------------- stage 2: out = relu(accum @ W + bias) ----------------
// 64 rows x 128 cols per block (313 blocks), 256 threads, thread tile 8x4.
// K-chunk 32. ALL inner LDS reads are b128 k-quads: per 4k per wave =
// 8 (A rows) + 4 (W) = 12 b128 ≈ 144 LDS cyc vs 128 FMA x 2 = 256 VALU cyc;
// model: 4 waves x 32 kq x 144 = 18.4k LDS-cyc/block x 313/256 ≈ 9.4 µs.
__global__ __launch_bounds__(256) void gcn_gemm(const float* __restrict__ A,
                                                const float* __restrict__ W,
                                                const float* __restrict__ bias,
                                                float* __restrict__ out) {
  __shared__ float Ws[32 * 132];  // 16.9 KB, [k][c] pad 132 (rows 528B, 16B-aligned)
  __shared__ float As[64 * 36];   // 9.2 KB,  [row][k] pad 36 (rows 144B, 16B-aligned)
  const int t = threadIdx.x;
  const int cx = t & 31;          // cols cx*4 .. cx*4+3
  const int ry = t >> 5;          // rows ry*8 .. ry*8+7
  const int row0 = blockIdx.x * 64;

  float acc[8][4];
#pragma unroll
  for (int r = 0; r < 8; ++r)
#pragma unroll
    for (int c = 0; c < 4; ++c) acc[r][c] = 0.f;

#pragma unroll
  for (int kc = 0; kc < F; kc += 32) {
    __syncthreads();  // protect As/Ws from previous chunk's readers
    // stage W: 32 k x 128 c = 1024 float4, 4/thread, coalesced
#pragma unroll
    for (int u = 0; u < 4; ++u) {
      int idx = u * 256 + t;
      int r = idx >> 5, q = idx & 31;
      *(float4*)(Ws + r * 132 + q * 4) = *(const float4*)(W + (kc + r) * F + q * 4);
    }
    // stage A: 64 rows x 32 k = 512 float4, 2/thread, coalesced (guarded)
#pragma unroll
    for (int u = 0; u < 2; ++u) {
      int idx = u * 256 + t;
      int r = idx >> 3, q = idx & 7;
      int grow = row0 + r;
      float4 v = make_float4(0.f, 0.f, 0.f, 0.f);
      if (grow < N_NODES) v = *(const float4*)(A + grow * F + kc + q * 4);
      *(float4*)(As + r * 36 + q * 4) = v;
    }
    __syncthreads();
#pragma unroll
    for (int kq = 0; kq < 8; ++kq) {
      float4 w0 = *(const float4*)(Ws + (kq * 4 + 0) * 132 + cx * 4);
      float4 w1 = *(const float4*)(Ws + (kq * 4 + 1) * 132 + cx * 4);
      float4 w2 = *(const float4*)(Ws + (kq * 4 + 2) * 132 + cx * 4);
      float4 w3 = *(const float4*)(Ws + (kq * 4 + 3) * 132 + cx * 4);
#pragma unroll
      for (int r = 0; r < 8; ++r) {
        float4 a = *(const float4*)(As + (ry * 8 + r) * 36 + kq * 4);
        acc[r][0] = fmaf(a.x, w0.x, acc[r][0]);
        acc[r][1] = fmaf(a.x, w0.y, acc[r][1]);
        acc[r][2] = fmaf(a.x, w0.z, acc[r][2]);
        acc[r][3] = fmaf(a.x, w0.w, acc[r][3]);
        acc[r][0] = fmaf(a.y, w1.x, acc[r][0]);
        acc[r][1] = fmaf(a.y, w1.y, acc[r][1]);
        acc[r][2] = fmaf(a.y, w1.z, acc[r][2]);
        acc[r][3] = fmaf(a.y, w1.w, acc[r][3]);
        acc[r][0] = fmaf(a.z, w2.x, acc[r][0]);
        acc[r][1] = fmaf(a.z, w2.y, acc[r][1]);
        acc[r][2] = fmaf(a.z, w2.z, acc[r][2]);
        acc[r][3] = fmaf(a.z, w2.w, acc[r][3]);
        acc[r][0] = fmaf(a.w, w3.x, acc[r][0]);
        acc[r][1] = fmaf(a.w, w3.y, acc[r][1]);
        acc[r][2] = fmaf(a.w, w3.z, acc[r][2]);
        acc[r][3] = fmaf(a.w, w3.w, acc[r][3]);
      }
    }
  }

  float4 bv = *(const float4*)(bias + cx * 4);
#pragma unroll
  for (int r = 0; r < 8; ++r) {
    int grow = row0 + ry * 8 + r;
    if (grow < N_NODES) {
      float4 o;
      o.x = fmaxf(acc[r][0] + bv.x, 0.f);
      o.y = fmaxf(acc[r][1] + bv.y, 0.f);
      o.z = fmaxf(acc[r][2] + bv.z, 0.f);
      o.w = fmaxf(acc[r][3] + bv.w, 0.f);
      *(float4*)(out + grow * F + cx * 4) = o;
    }
  }
}

extern "C" void kernel_launch(void* const* d_in, const int* in_sizes, int n_in,
                              void* d_out, int out_size, void* d_ws, size_t ws_size,
                              hipStream_t stream) {
  const float* h = (const float*)d_in[0];
  const float* norm = (const float*)d_in[1];
  const float* weight = (const float*)d_in[2];
  const float* bias = (const float*)d_in[3];
  const int* nbr = (const int*)d_in[4];
  const int* deg = (const int*)d_in[5];
  float* out = (float*)d_out;
  float* accum = (float*)d_ws;  // 20000*128*4 = 10.24 MB scratch

  gcn_stage1<<<N_NODES / 2, 256, 0, stream>>>(h, norm, nbr, deg, accum);
  gcn_gemm<<<(N_NODES + 63) / 64, 256, 0, stream>>>(accum, weight, bias, out);
}

// Round 6
// 467.098 us; speedup vs baseline: 2.0394x; 2.0394x over previous
//
#include <hip/hip_runtime.h>
#include <cfloat>
#include <cmath>

#define N_NODES 20000
#define MAXD 32
#define F 128

// ---------------- stage 1: trimmed-mean aggregation (register version) -------

// Batcher odd-even mergesort network, ascending, fully unrolled.
// CE counts: SZ=4:5, 8:19, 16:63, 32:191.
template <int SZ>
__device__ __forceinline__ void oe_sort(float (&a)[SZ]) {
#pragma unroll
  for (int p = 1; p < SZ; p <<= 1) {
#pragma unroll
    for (int q = p; q >= 1; q >>= 1) {
#pragma unroll
      for (int j = q % p; j <= SZ - 1 - q; j += 2 * q) {
#pragma unroll
        for (int i = 0; i < q; ++i) {
          int x = i + j, y = i + j + q;
          if (y < SZ && (x / (2 * p)) == (y / (2 * p))) {
            float mn = fminf(a[x], a[y]);
            float mx = fmaxf(a[x], a[y]);
            a[x] = mn;
            a[y] = mx;
          }
        }
      }
    }
  }
}

// extract element at (wave-uniform) position p from a statically-indexed register array
template <int SZ>
__device__ __forceinline__ float extract_pos(const float (&k)[SZ], int p) {
  float sel[SZ];
#pragma unroll
  for (int i = 0; i < SZ; ++i) sel[i] = k[i];
#pragma unroll
  for (int w = SZ >> 1; w >= 1; w >>= 1) {
    bool take = (p & w) != 0;
#pragma unroll
    for (int i = 0; i < w; ++i) sel[i] = take ? sel[i + w] : sel[i];
  }
  return sel[0];
}

// Exact trimmed sum: payloads (key*norm_src) whose STABLE rank (key asc, ties
// by slot — matches jnp.argsort) lies in [b, n-b).
// Fast path: when sorted[b-1] < sorted[b] and sorted[n-b-1] < sorted[n-b],
// rank-membership == value-membership in [lo, hi] (exact, incl. lo==hi runs).
// Slow path (rare boundary ties): exact stable-rank scan.
template <int SZ>
__device__ __forceinline__ float trimmed_sum(const float* __restrict__ h,
                                             const float* __restrict__ norm,
                                             const int* __restrict__ nbr_row,
                                             int n, int f, int b) {
  float ko[SZ];
  float nrm[SZ];  // wave-uniform -> SGPRs
#pragma unroll
  for (int d = 0; d < SZ; ++d) {
    if (d < n) {  // uniform branch (n wave-uniform)
      int src = nbr_row[d];       // scalar load
      nrm[d] = norm[src];         // scalar load
      ko[d] = h[src * F + f];     // vector load, coalesced 256B/wave
    } else {
      nrm[d] = 0.f;
      ko[d] = FLT_MAX;            // pads sort past all valid keys
    }
  }

  float k[SZ];
#pragma unroll
  for (int d = 0; d < SZ; ++d) k[d] = ko[d];
  oe_sort<SZ>(k);

  const float lo  = extract_pos<SZ>(k, b);          // rank b (kept)
  const float hi  = extract_pos<SZ>(k, n - b - 1);  // rank n-b-1 (kept)
  const float lom = extract_pos<SZ>(k, b - 1);      // rank b-1 (trimmed)
  const float him = extract_pos<SZ>(k, n - b);      // rank n-b (trimmed)

  float sum = 0.f;
  if ((lom < lo) & (hi < him)) {
#pragma unroll
    for (int d = 0; d < SZ; ++d) {
      bool keep = (ko[d] >= lo) & (ko[d] <= hi);  // pads (FLT_MAX) fail
      sum = fmaf(keep ? ko[d] : 0.f, nrm[d], sum);
    }
  } else {
    int c_lt_lo = 0, c_lt_hi = 0;
#pragma unroll
    for (int d = 0; d < SZ; ++d) {
      c_lt_lo += (ko[d] < lo) ? 1 : 0;
      c_lt_hi += (ko[d] < hi) ? 1 : 0;
    }
    int run_lo = 0, run_hi = 0;
    const int nb = n - b;
#pragma unroll
    for (int d = 0; d < SZ; ++d) {
      const float kd = ko[d];
      const float m = kd * nrm[d];  // pads: FLT_MAX*0 = 0
      const bool eql = (kd == lo);
      const bool eqh = (kd == hi);
      const bool lh = (lo < hi);
      const bool btw = (kd > lo) & (kd < hi);
      const int r_lo = c_lt_lo + run_lo;  // stable rank if kd==lo
      const int r_hi = c_lt_hi + run_hi;  // stable rank if kd==hi
      const bool inc = btw
                     | (eql & (r_lo >= b) & (lh | (r_lo < nb)))
                     | (lh & eqh & (r_hi < nb));
      sum += inc ? m : 0.f;
      run_lo += eql ? 1 : 0;
      run_hi += eqh ? 1 : 0;
    }
  }
  return sum;
}

// 256 threads = 2 nodes per block (4 waves). Control flow wave-uniform.
__global__ __launch_bounds__(256) void gcn_stage1(const float* __restrict__ h,
                                                  const float* __restrict__ norm,
                                                  const int* __restrict__ nbr,
                                                  const int* __restrict__ deg,
                                                  float* __restrict__ accum) {
  const int t = threadIdx.x;
  const int i = blockIdx.x * 2 + (t >> 7);
  const int f = t & 127;
  const int n = deg[i];            // wave-uniform
  const float ni = norm[i];
  const float hif = h[i * F + f];
  const int idx = i * F + f;

  if (n <= 3) {  // N_NEIGH_THRESHOLD branch
    accum[idx] = (float)n * hif * ni * ni;
    return;
  }

  int b = n / 2 - (1 - (n & 1));
  int bcap = (int)floorf((float)n * 0.45f);
  b = b < bcap ? b : bcap;
  b = b > 1 ? b : 1;

  const int* nbr_row = nbr + i * MAXD;
  float ts;
  if (n <= 4)       ts = trimmed_sum<4>(h, norm, nbr_row, n, f, b);
  else if (n <= 8)  ts = trimmed_sum<8>(h, norm, nbr_row, n, f, b);
  else if (n <= 16) ts = trimmed_sum<16>(h, norm, nbr_row, n, f, b);
  else              ts = trimmed_sum<32>(h, norm, nbr_row, n, f, b);

  accum[idx] = (ts + hif * ni * (float)(2 * b)) * ni;
}

// ---------------- stage 2: out = relu(accum @ W + bias) ----------------
// Round-3 design verbatim (inferred ~17 µs, no spill): 256 threads,
// 32 rows x 128 cols per block, k-chunk=32, 4x4 thread tile.
__global__ __launch_bounds__(256) void gcn_gemm(const float* __restrict__ A,
                                                const float* __restrict__ W,
                                                const float* __restrict__ bias,
                                                float* __restrict__ out) {
  __shared__ float Ws[32 * F];   // 16 KB: k-chunk of W, [k][c]
  __shared__ float As[32 * 36];  // 4.6 KB: [row][k], pad 36 keeps 16B align
  const int t = threadIdx.x;
  const int tx = t & 31;         // col group: cols tx*4..tx*4+3
  const int ty = t >> 5;         // row group: rows ty*4..ty*4+3
  const int row0 = blockIdx.x * 32;
  const int ar = t >> 3, ak = t & 7;  // A staging coords

  float acc[4][4];
#pragma unroll
  for (int r = 0; r < 4; ++r)
#pragma unroll
    for (int c = 0; c < 4; ++c) acc[r][c] = 0.f;

#pragma unroll
  for (int kc = 0; kc < F; kc += 32) {
    __syncthreads();  // protect As/Ws from previous chunk's readers
    // stage A: 32 rows x 32 k (1 float4/thread, coalesced)
    float4 av = *(const float4*)(A + (row0 + ar) * F + kc + ak * 4);
    *(float4*)(As + ar * 36 + ak * 4) = av;
    // stage W: 32 k x 128 c = 1024 float4 (4/thread, fully coalesced)
#pragma unroll
    for (int u = 0; u < 4; ++u) {
      int idx2 = u * 256 + t;
      *(float4*)(Ws + idx2 * 4) = *(const float4*)(W + kc * F + idx2 * 4);
    }
    __syncthreads();
#pragma unroll 8
    for (int k = 0; k < 32; ++k) {
      float4 w4 = *(const float4*)(Ws + k * F + tx * 4);
      float a0 = As[(ty * 4 + 0) * 36 + k];
      float a1 = As[(ty * 4 + 1) * 36 + k];
      float a2 = As[(ty * 4 + 2) * 36 + k];
      float a3 = As[(ty * 4 + 3) * 36 + k];
      acc[0][0] = fmaf(a0, w4.x, acc[0][0]); acc[0][1] = fmaf(a0, w4.y, acc[0][1]);
      acc[0][2] = fmaf(a0, w4.z, acc[0][2]); acc[0][3] = fmaf(a0, w4.w, acc[0][3]);
      acc[1][0] = fmaf(a1, w4.x, acc[1][0]); acc[1][1] = fmaf(a1, w4.y, acc[1][1]);
      acc[1][2] = fmaf(a1, w4.z, acc[1][2]); acc[1][3] = fmaf(a1, w4.w, acc[1][3]);
      acc[2][0] = fmaf(a2, w4.x, acc[2][0]); acc[2][1] = fmaf(a2, w4.y, acc[2][1]);
      acc[2][2] = fmaf(a2, w4.z, acc[2][2]); acc[2][3] = fmaf(a2, w4.w, acc[2][3]);
      acc[3][0] = fmaf(a3, w4.x, acc[3][0]); acc[3][1] = fmaf(a3, w4.y, acc[3][1]);
      acc[3][2] = fmaf(a3, w4.z, acc[3][2]); acc[3][3] = fmaf(a3, w4.w, acc[3][3]);
    }
  }

  float4 bv = *(const float4*)(bias + tx * 4);
#pragma unroll
  for (int r = 0; r < 4; ++r) {
    float4 o;
    o.x = fmaxf(acc[r][0] + bv.x, 0.f);
    o.y = fmaxf(acc[r][1] + bv.y, 0.f);
    o.z = fmaxf(acc[r][2] + bv.z, 0.f);
    o.w = fmaxf(acc[r][3] + bv.w, 0.f);
    *(float4*)(out + (row0 + ty * 4 + r) * F + tx * 4) = o;
  }
}

extern "C" void kernel_launch(void* const* d_in, const int* in_sizes, int n_in,
                              void* d_out, int out_size, void* d_ws, size_t ws_size,
                              hipStream_t stream) {
  const float* h = (const float*)d_in[0];
  const float* norm = (const float*)d_in[1];
  const float* weight = (const float*)d_in[2];
  const float* bias = (const float*)d_in[3];
  const int* nbr = (const int*)d_in[4];
  const int* deg = (const int*)d_in[5];
  float* out = (float*)d_out;
  float* accum = (float*)d_ws;  // 20000*128*4 = 10.24 MB scratch

  gcn_stage1<<<N_NODES / 2, 256, 0, stream>>>(h, norm, nbr, deg, accum);
  gcn_gemm<<<N_NODES / 32, 256, 0, stream>>>(accum, weight, bias, out);
}

// Round 7
// 134.854 us; speedup vs baseline: 7.0640x; 3.4637x over previous
//
#include <hip/hip_runtime.h>
#include <cfloat>
#include <cmath>

#define N_NODES 20000
#define MAXD 32
#define F 128

// ---------------- stage 1: trimmed-mean aggregation (round-2 verbatim) -------
// CRITICAL: node index i = blockIdx.x (compile-time block-uniform). Deriving i
// from threadIdx (round 5/6) forces n/b/nbr/nrm into VGPRs -> ~10x VALU blowup
// (415 us vs 57 us measured). Do not change the 1-node-per-128-thread-block shape.

// Batcher odd-even mergesort network, ascending, fully unrolled.
// CE counts: SZ=4:5, 8:19, 16:63, 32:191.
template <int SZ>
__device__ __forceinline__ void oe_sort(float (&a)[SZ]) {
#pragma unroll
  for (int p = 1; p < SZ; p <<= 1) {
#pragma unroll
    for (int q = p; q >= 1; q >>= 1) {
#pragma unroll
      for (int j = q % p; j <= SZ - 1 - q; j += 2 * q) {
#pragma unroll
        for (int i = 0; i < q; ++i) {
          int x = i + j, y = i + j + q;
          if (y < SZ && (x / (2 * p)) == (y / (2 * p))) {
            float mn = fminf(a[x], a[y]);
            float mx = fmaxf(a[x], a[y]);
            a[x] = mn;
            a[y] = mx;
          }
        }
      }
    }
  }
}

// extract element at (block-uniform) position p from a statically-indexed register array
template <int SZ>
__device__ __forceinline__ float extract_pos(const float (&k)[SZ], int p) {
  float sel[SZ];
#pragma unroll
  for (int i = 0; i < SZ; ++i) sel[i] = k[i];
#pragma unroll
  for (int w = SZ >> 1; w >= 1; w >>= 1) {
    bool take = (p & w) != 0;  // p scalar (blockIdx-derived) -> s_cselect chain
#pragma unroll
    for (int i = 0; i < w; ++i) sel[i] = take ? sel[i + w] : sel[i];
  }
  return sel[0];
}

// Exact trimmed sum: payloads (key*norm_src) whose STABLE rank (key asc, ties
// by slot — matches jnp.argsort) lies in [b, n-b).
// Fast path: when sorted[b-1] < sorted[b] and sorted[n-b-1] < sorted[n-b],
// rank-membership == value-membership in [lo, hi] (exact, incl. lo==hi runs).
// Slow path (rare boundary ties): exact stable-rank scan.
template <int SZ>
__device__ __forceinline__ float trimmed_sum(const float* __restrict__ h,
                                             const float* __restrict__ norm,
                                             const int* __restrict__ nbr_row,
                                             int n, int f, int b) {
  float ko[SZ];
  float nrm[SZ];  // block-uniform -> SGPRs
#pragma unroll
  for (int d = 0; d < SZ; ++d) {
    if (d < n) {  // uniform branch (n block-uniform)
      int src = nbr_row[d];       // scalar load
      nrm[d] = norm[src];         // scalar load
      ko[d] = h[src * F + f];     // vector load, coalesced 256B/wave
    } else {
      nrm[d] = 0.f;
      ko[d] = FLT_MAX;            // pads sort past all valid keys
    }
  }

  float k[SZ];
#pragma unroll
  for (int d = 0; d < SZ; ++d) k[d] = ko[d];
  oe_sort<SZ>(k);

  const float lo  = extract_pos<SZ>(k, b);          // rank b (kept)
  const float hi  = extract_pos<SZ>(k, n - b - 1);  // rank n-b-1 (kept)
  const float lom = extract_pos<SZ>(k, b - 1);      // rank b-1 (trimmed)
  const float him = extract_pos<SZ>(k, n - b);      // rank n-b (trimmed)

  float sum = 0.f;
  if ((lom < lo) & (hi < him)) {
#pragma unroll
    for (int d = 0; d < SZ; ++d) {
      bool keep = (ko[d] >= lo) & (ko[d] <= hi);  // pads (FLT_MAX) fail
      sum = fmaf(keep ? ko[d] : 0.f, nrm[d], sum);
    }
  } else {
    int c_lt_lo = 0, c_lt_hi = 0;
#pragma unroll
    for (int d = 0; d < SZ; ++d) {
      c_lt_lo += (ko[d] < lo) ? 1 : 0;
      c_lt_hi += (ko[d] < hi) ? 1 : 0;
    }
    int run_lo = 0, run_hi = 0;
    const int nb = n - b;
#pragma unroll
    for (int d = 0; d < SZ; ++d) {
      const float kd = ko[d];
      const float m = kd * nrm[d];  // pads: FLT_MAX*0 = 0
      const bool eql = (kd == lo);
      const bool eqh = (kd == hi);
      const bool lh = (lo < hi);
      const bool btw = (kd > lo) & (kd < hi);
      const int r_lo = c_lt_lo + run_lo;  // stable rank if kd==lo
      const int r_hi = c_lt_hi + run_hi;  // stable rank if kd==hi
      const bool inc = btw
                     | (eql & (r_lo >= b) & (lh | (r_lo < nb)))
                     | (lh & eqh & (r_hi < nb));
      sum += inc ? m : 0.f;
      run_lo += eql ? 1 : 0;
      run_hi += eqh ? 1 : 0;
    }
  }
  return sum;
}

__global__ __launch_bounds__(128) void gcn_stage1(const float* __restrict__ h,
                                                  const float* __restrict__ norm,
                                                  const int* __restrict__ nbr,
                                                  const int* __restrict__ deg,
                                                  float* __restrict__ accum) {
  const int i = blockIdx.x;       // MUST stay blockIdx-derived (see header note)
  const int f = threadIdx.x;
  const int n = deg[i];           // scalar
  const float ni = norm[i];
  const float hif = h[i * F + f];
  const int idx = i * F + f;

  if (n <= 3) {  // N_NEIGH_THRESHOLD branch
    accum[idx] = (float)n * hif * ni * ni;
    return;
  }

  int b = n / 2 - (1 - (n & 1));
  int bcap = (int)floorf((float)n * 0.45f);
  b = b < bcap ? b : bcap;
  b = b > 1 ? b : 1;

  const int* nbr_row = nbr + i * MAXD;
  float ts;
  if (n <= 4)       ts = trimmed_sum<4>(h, norm, nbr_row, n, f, b);
  else if (n <= 8)  ts = trimmed_sum<8>(h, norm, nbr_row, n, f, b);
  else if (n <= 16) ts = trimmed_sum<16>(h, norm, nbr_row, n, f, b);
  else              ts = trimmed_sum<32>(h, norm, nbr_row, n, f, b);

  accum[idx] = (ts + hif * ni * (float)(2 * b)) * ni;
}

// ---------------- stage 2: out = relu(accum @ W + bias) (round-3 verbatim) ---
// 256 threads, 32 rows x 128 cols per block, k-chunk=32, 4x4 thread tile.
// Measured-by-subtraction ~17 us; known non-spilling shape. Do NOT widen the
// thread tile or fully unroll bigger shapes: 8x4 + full unroll spilled (VGPR=256,
// 387 MB scratch fetch, 508 us — round 5).
__global__ __launch_bounds__(256) void gcn_gemm(const float* __restrict__ A,
                                                const float* __restrict__ W,
                                                const float* __restrict__ bias,
                                                float* __restrict__ out) {
  __shared__ float Ws[32 * F];   // 16 KB: k-chunk of W, [k][c]
  __shared__ float As[32 * 36];  // 4.6 KB: [row][k], pad 36 keeps 16B align
  const int t = threadIdx.x;
  const int tx = t & 31;         // col group: cols tx*4..tx*4+3
  const int ty = t >> 5;         // row group: rows ty*4..ty*4+3
  const int row0 = blockIdx.x * 32;
  const int ar = t >> 3, ak = t & 7;  // A staging coords

  float acc[4][4];
#pragma unroll
  for (int r = 0; r < 4; ++r)
#pragma unroll
    for (int c = 0; c < 4; ++c) acc[r][c] = 0.f;

#pragma unroll
  for (int kc = 0; kc < F; kc += 32) {
    __syncthreads();  // protect As/Ws from previous chunk's readers
    // stage A: 32 rows x 32 k (1 float4/thread, coalesced)
    float4 av = *(const float4*)(A + (row0 + ar) * F + kc + ak * 4);
    *(float4*)(As + ar * 36 + ak * 4) = av;
    // stage W: 32 k x 128 c = 1024 float4 (4/thread, fully coalesced)
#pragma unroll
    for (int u = 0; u < 4; ++u) {
      int idx2 = u * 256 + t;
      *(float4*)(Ws + idx2 * 4) = *(const float4*)(W + kc * F + idx2 * 4);
    }
    __syncthreads();
#pragma unroll 8
    for (int k = 0; k < 32; ++k) {
      float4 w4 = *(const float4*)(Ws + k * F + tx * 4);
      float a0 = As[(ty * 4 + 0) * 36 + k];
      float a1 = As[(ty * 4 + 1) * 36 + k];
      float a2 = As[(ty * 4 + 2) * 36 + k];
      float a3 = As[(ty * 4 + 3) * 36 + k];
      acc[0][0] = fmaf(a0, w4.x, acc[0][0]); acc[0][1] = fmaf(a0, w4.y, acc[0][1]);
      acc[0][2] = fmaf(a0, w4.z, acc[0][2]); acc[0][3] = fmaf(a0, w4.w, acc[0][3]);
      acc[1][0] = fmaf(a1, w4.x, acc[1][0]); acc[1][1] = fmaf(a1, w4.y, acc[1][1]);
      acc[1][2] = fmaf(a1, w4.z, acc[1][2]); acc[1][3] = fmaf(a1, w4.w, acc[1][3]);
      acc[2][0] = fmaf(a2, w4.x, acc[2][0]); acc[2][1] = fmaf(a2, w4.y, acc[2][1]);
      acc[2][2] = fmaf(a2, w4.z, acc[2][2]); acc[2][3] = fmaf(a2, w4.w, acc[2][3]);
      acc[3][0] = fmaf(a3, w4.x, acc[3][0]); acc[3][1] = fmaf(a3, w4.y, acc[3][1]);
      acc[3][2] = fmaf(a3, w4.z, acc[3][2]); acc[3][3] = fmaf(a3, w4.w, acc[3][3]);
    }
  }

  float4 bv = *(const float4*)(bias + tx * 4);
#pragma unroll
  for (int r = 0; r < 4; ++r) {
    float4 o;
    o.x = fmaxf(acc[r][0] + bv.x, 0.f);
    o.y = fmaxf(acc[r][1] + bv.y, 0.f);
    o.z = fmaxf(acc[r][2] + bv.z, 0.f);
    o.w = fmaxf(acc[r][3] + bv.w, 0.f);
    *(float4*)(out + (row0 + ty * 4 + r) * F + tx * 4) = o;
  }
}

extern "C" void kernel_launch(void* const* d_in, const int* in_sizes, int n_in,
                              void* d_out, int out_size, void* d_ws, size_t ws_size,
                              hipStream_t stream) {
  const float* h = (const float*)d_in[0];
  const float* norm = (const float*)d_in[1];
  const float* weight = (const float*)d_in[2];
  const float* bias = (const float*)d_in[3];
  const int* nbr = (const int*)d_in[4];
  const int* deg = (const int*)d_in[5];
  float* out = (float*)d_out;
  float* accum = (float*)d_ws;  // 20000*128*4 = 10.24 MB scratch

  gcn_stage1<<<N_NODES, 128, 0, stream>>>(h, norm, nbr, deg, accum);
  gcn_gemm<<<N_NODES / 32, 256, 0, stream>>>(accum, weight, bias, out);
}